// Round 1
// baseline (95.902 us; speedup 1.0000x reference)
//
#include <hip/hip_runtime.h>

#define NS 9

// out[b,h,A,C,j] = sum_d q[b,h,A,C,d]*relw[63+j-C,d] + q[b,h,C,A,d]*relh[63+j-C,d]
// B=16, heads=8, A,C in [0,64), d in [0,64), j in [0,9)
// wave: lanes = A (64), C uniform per wave (readfirstlane -> scalar rel loads)
// block: 4 waves = 4 consecutive C values; grid: 128 bh * 16 c-groups.
// blockIdx decode keeps same-(b,h) blocks on the same XCD (id % 8 == bh % 8)
// so the 1 MiB q slab for a (b,h) is L2-resident across its 2x reads.

__global__ __launch_bounds__(256, 4) void relpos_kernel(
    const float* __restrict__ q,
    const float* __restrict__ relh,
    const float* __restrict__ relw,
    float* __restrict__ out)
{
    const int bh = blockIdx.x & 127;   // b*8 + h
    const int g  = blockIdx.x >> 7;    // c-group, 0..15
    const int wv = threadIdx.x >> 6;   // wave in block, 0..3
    const int a  = threadIdx.x & 63;   // lane = A

    const int c  = __builtin_amdgcn_readfirstlane(g * 4 + wv); // uniform C
    const int r0 = 63 - c;             // rel row base; rows r0..r0+8 in [0,72)

    const float* __restrict__ q1 = q + ((((size_t)bh << 6) + a) * 64 + c) * 64;
    const float* __restrict__ q2 = q + ((((size_t)bh << 6) + c) * 64 + a) * 64;
    const float* __restrict__ w0 = relw + (size_t)r0 * 64;
    const float* __restrict__ h0 = relh + (size_t)r0 * 64;

    float acc[NS];
#pragma unroll
    for (int j = 0; j < NS; ++j) acc[j] = 0.f;

#pragma unroll
    for (int ch = 0; ch < 16; ++ch) {
        const float4 x1 = *reinterpret_cast<const float4*>(q1 + ch * 4);
        const float4 x2 = *reinterpret_cast<const float4*>(q2 + ch * 4);
#pragma unroll
        for (int j = 0; j < NS; ++j) {
            const float4 w  = *reinterpret_cast<const float4*>(w0 + j * 64 + ch * 4);
            const float4 hh = *reinterpret_cast<const float4*>(h0 + j * 64 + ch * 4);
            acc[j] += x1.x * w.x  + x1.y * w.y  + x1.z * w.z  + x1.w * w.w
                    + x2.x * hh.x + x2.y * hh.y + x2.z * hh.z + x2.w * hh.w;
        }
    }

    float* __restrict__ o = out + ((((size_t)bh << 6) + a) * 64 + c) * NS;
#pragma unroll
    for (int j = 0; j < NS; ++j) o[j] = acc[j];
}

extern "C" void kernel_launch(void* const* d_in, const int* in_sizes, int n_in,
                              void* d_out, int out_size, void* d_ws, size_t ws_size,
                              hipStream_t stream) {
    const float* q    = (const float*)d_in[0];
    // d_in[1] = H (int), d_in[2] = W (int) -- fixed at 64 for this problem
    const float* relh = (const float*)d_in[3];
    const float* relw = (const float*)d_in[4];
    float* out = (float*)d_out;

    // grid: 16 c-groups x 128 (b,h) pairs; block: 4 waves (4 C values)
    relpos_kernel<<<dim3(2048), dim3(256), 0, stream>>>(q, relh, relw, out);
}

// Round 2
// 63.141 us; speedup vs baseline: 1.5189x; 1.5189x over previous
//
#include <hip/hip_runtime.h>
#include <stdint.h>

#define NS 9

// out[b,h,A,C,j] = sum_d q[b,h,A,C,d]*relw[63+j-C,d] + q[b,h,C,A,d]*relh[63+j-C,d]
// Block = 4 waves = 4 consecutive C (c0 = 4g); lane = A. Two phases share one
// 64 KiB LDS tile:
//   phase 1: qt row r = wv*64+a  <- q[bh, c0+wv, a, :]   (term2, contiguous src)
//   phase 2: qt row r = wv*64+a  <- q[bh, a, c0+wv, :]   (term1, 4x256B rows/instr)
// Staged via global_load_lds (16B/lane, linear LDS dest) with XOR-swizzled
// global source: slot s of row r holds global chunk s ^ (r&7); compute reads
// slot ch ^ (r&7)  ->  ~8-way residual bank conflict instead of 32-way.
// Rel tables read as wave-uniform global loads (c is readfirstlane-uniform ->
// compiler emits s_load; operands ride the scalar pipe).

__device__ __forceinline__ void gload_lds16(const void* g, void* l) {
    __builtin_amdgcn_global_load_lds(
        (const __attribute__((address_space(1))) uint32_t*)g,
        (__attribute__((address_space(3))) uint32_t*)l, 16, 0, 0);
}

__global__ __launch_bounds__(256, 2) void relpos_kernel(
    const float* __restrict__ q,
    const float* __restrict__ relh,
    const float* __restrict__ relw,
    float* __restrict__ out)
{
    __shared__ float qt[256 * 64];   // 64 KiB: 256 rows x 64 floats (16 chunks)

    const int bh   = blockIdx.x & 127;   // b*8 + h
    const int g    = blockIdx.x >> 7;    // c-group 0..15
    const int lane = threadIdx.x & 63;   // = A
    const int wvu  = __builtin_amdgcn_readfirstlane(threadIdx.x >> 6); // wave 0..3
    const int c0   = g << 2;
    const int c    = __builtin_amdgcn_readfirstlane(c0 + wvu);         // uniform C
    const int a    = lane;

    const size_t qslab = (size_t)bh << 18;   // bh * 64*64*64

    float acc[NS];
#pragma unroll
    for (int j = 0; j < NS; ++j) acc[j] = 0.f;

    const int r2 = (wvu << 6) | a;           // this thread's qt row (both phases)
    const float* __restrict__ w0 = relw + (size_t)(63 - c) * 64;
    const float* __restrict__ h0 = relh + (size_t)(63 - c) * 64;

    // ---------- phase 1: stage q2 tile, compute term2 (relh) ----------
#pragma unroll
    for (int i = 0; i < 16; ++i) {
        const int ck   = ((wvu << 4) + i) * 64 + lane;   // global chunk-slot id
        const int r    = ck >> 4;                        // row 0..255
        const int slot = ck & 15;
        const int gch  = slot ^ (r & 7);                 // pre-swizzled source
        // q2 row r: q[bh, c0 + (r>>6), r&63, :]
        const float* gp = q + qslab + (size_t)(c0 + (r >> 6)) * 4096
                            + (size_t)(r & 63) * 64 + gch * 4;
        gload_lds16(gp, (char*)qt + ((size_t)((wvu << 4) + i) << 10));
    }
    __syncthreads();

#pragma unroll
    for (int ch = 0; ch < 16; ++ch) {
        const float4 x = *reinterpret_cast<const float4*>(
            &qt[(r2 << 6) + ((ch ^ (r2 & 7)) << 2)]);
#pragma unroll
        for (int j = 0; j < NS; ++j) {
            const float4 hv = *reinterpret_cast<const float4*>(h0 + (j << 6) + (ch << 2));
            acc[j] = fmaf(x.x, hv.x, fmaf(x.y, hv.y,
                     fmaf(x.z, hv.z, fmaf(x.w, hv.w, acc[j]))));
        }
    }
    __syncthreads();   // everyone done reading qt before phase-2 overwrite

    // ---------- phase 2: stage q1 tile, compute term1 (relw) ----------
#pragma unroll
    for (int i = 0; i < 16; ++i) {
        const int ck   = ((wvu << 4) + i) * 64 + lane;
        const int r    = ck >> 4;
        const int slot = ck & 15;
        const int gch  = slot ^ (r & 7);
        // q1 row r: q[bh, r&63, c0 + (r>>6), :]
        const float* gp = q + qslab + (size_t)(r & 63) * 4096
                            + (size_t)(c0 + (r >> 6)) * 64 + gch * 4;
        gload_lds16(gp, (char*)qt + ((size_t)((wvu << 4) + i) << 10));
    }
    __syncthreads();

#pragma unroll
    for (int ch = 0; ch < 16; ++ch) {
        const float4 x = *reinterpret_cast<const float4*>(
            &qt[(r2 << 6) + ((ch ^ (r2 & 7)) << 2)]);
#pragma unroll
        for (int j = 0; j < NS; ++j) {
            const float4 wv4 = *reinterpret_cast<const float4*>(w0 + (j << 6) + (ch << 2));
            acc[j] = fmaf(x.x, wv4.x, fmaf(x.y, wv4.y,
                     fmaf(x.z, wv4.z, fmaf(x.w, wv4.w, acc[j]))));
        }
    }

    // ---------- store ----------
    float* __restrict__ o = out + (((size_t)bh * 64 + a) * 64 + c) * NS;
#pragma unroll
    for (int j = 0; j < NS; ++j) o[j] = acc[j];
}

extern "C" void kernel_launch(void* const* d_in, const int* in_sizes, int n_in,
                              void* d_out, int out_size, void* d_ws, size_t ws_size,
                              hipStream_t stream) {
    const float* q    = (const float*)d_in[0];
    const float* relh = (const float*)d_in[3];
    const float* relw = (const float*)d_in[4];
    float* out = (float*)d_out;

    // grid: 16 c-groups x 128 (b,h); same-bh blocks are 128 apart -> same XCD
    relpos_kernel<<<dim3(2048), dim3(256), 0, stream>>>(q, relh, relw, out);
}

// Round 3
// 59.723 us; speedup vs baseline: 1.6058x; 1.0572x over previous
//
#include <hip/hip_runtime.h>
#include <stdint.h>

#define NS 9

// out[b,h,A,C,j] = sum_d q[b,h,A,C,d]*relw[63+j-C,d] + q[b,h,C,A,d]*relh[63+j-C,d]
// Block = 4 waves, wave wvu owns C = 4*g + wvu; lane = A. Per-wave pipeline,
// NO block barriers (each wave reads only the LDS it staged):
//   4 stages: {q2,d0} {q2,d1} {q1,d0} {q1,d1}, 8 KiB each (64 A-rows x 32 d),
//   2-deep double buffer, counted s_waitcnt vmcnt(8) between stages.
// LDS dest linear (global_load_lds requirement); global source pre-XOR-swizzled
// (slot s of row r holds chunk s^(r&7)); compute reads slot ch^(a&7).
// Rel-table reads are wave-uniform (c readfirstlane'd) -> scalar s_loads.

__device__ __forceinline__ void gload_lds16(const void* g, void* l) {
    __builtin_amdgcn_global_load_lds(
        (const __attribute__((address_space(1))) uint32_t*)g,
        (__attribute__((address_space(3))) uint32_t*)l, 16, 0, 0);
}

#define WAIT_VMCNT(N) do { \
    __builtin_amdgcn_sched_barrier(0); \
    asm volatile("s_waitcnt vmcnt(" #N ")" ::: "memory"); \
    __builtin_amdgcn_sched_barrier(0); } while (0)

#define WAIT_LGKM0 do { \
    __builtin_amdgcn_sched_barrier(0); \
    asm volatile("s_waitcnt lgkmcnt(0)" ::: "memory"); \
    __builtin_amdgcn_sched_barrier(0); } while (0)

__global__ __launch_bounds__(256, 2) void relpos_kernel(
    const float* __restrict__ q,
    const float* __restrict__ relh,
    const float* __restrict__ relw,
    float* __restrict__ out)
{
    __shared__ float qt[4][2][2048];   // 4 waves x 2 bufs x 8 KiB = 64 KiB

    const int bh   = blockIdx.x & 127;   // b*8 + h
    const int g    = blockIdx.x >> 7;    // c-group 0..15
    const int lane = threadIdx.x & 63;   // = A
    const int wvu  = __builtin_amdgcn_readfirstlane(threadIdx.x >> 6);
    const int c    = __builtin_amdgcn_readfirstlane((g << 2) + wvu);
    const int a    = lane;

    const size_t qslab = (size_t)bh << 18;        // bh * 64*64*64
    const float* __restrict__ h0 = relh + (size_t)(63 - c) * 64;
    const float* __restrict__ w0 = relw + (size_t)(63 - c) * 64;

    float* const buf0 = &qt[wvu][0][0];
    float* const buf1 = &qt[wvu][1][0];

    float acc[NS];
#pragma unroll
    for (int j = 0; j < NS; ++j) acc[j] = 0.f;

    // ---- stage issue: 8 x global_load_lds (1 KiB each) per 8 KiB sub-tile ----
    // phase 0: q2 row r = q[bh, c, r, :]   phase 1: q1 row r = q[bh, r, c, :]
    auto stage = [&](float* buf, int phase, int h) {
#pragma unroll
        for (int i = 0; i < 8; ++i) {
            const int ck  = (i << 6) | lane;        // chunk-slot 0..511
            const int r   = ck >> 3;                // A-row 0..63
            const int gch = (ck & 7) ^ (r & 7);     // pre-swizzled source chunk
            const float* gp = (phase == 0)
                ? q + qslab + (size_t)c * 4096 + (size_t)r * 64 + (h << 5) + (gch << 2)
                : q + qslab + (size_t)r * 4096 + (size_t)c * 64 + (h << 5) + (gch << 2);
            gload_lds16(gp, buf + (i << 8));        // linear dest, i*1024 B
        }
    };

    auto compute = [&](const float* buf, const float* rel, int h) {
#pragma unroll
        for (int ch = 0; ch < 8; ++ch) {
            const float4 x = *reinterpret_cast<const float4*>(
                &buf[(a << 5) + ((ch ^ (a & 7)) << 2)]);
#pragma unroll
            for (int j = 0; j < NS; ++j) {
                const float4 rv = *reinterpret_cast<const float4*>(
                    &rel[(j << 6) + (h << 5) + (ch << 2)]);
                acc[j] = fmaf(x.x, rv.x, fmaf(x.y, rv.y,
                         fmaf(x.z, rv.z, fmaf(x.w, rv.w, acc[j]))));
            }
        }
    };

    // ---- 4-stage pipeline, 2-deep ----
    stage(buf0, 0, 0);            // S0
    stage(buf1, 0, 1);            // S1
    WAIT_VMCNT(8);                // S0 landed
    compute(buf0, h0, 0);
    WAIT_LGKM0;                   // buf0 reads done before overwrite
    stage(buf0, 1, 0);            // S2
    WAIT_VMCNT(8);                // S1 landed
    compute(buf1, h0, 1);
    WAIT_LGKM0;
    stage(buf1, 1, 1);            // S3
    WAIT_VMCNT(8);                // S2 landed
    compute(buf0, w0, 0);
    WAIT_VMCNT(0);                // S3 landed
    compute(buf1, w0, 1);

    // ---- store ----
    float* __restrict__ o = out + (((size_t)bh * 64 + a) * 64 + c) * NS;
#pragma unroll
    for (int j = 0; j < NS; ++j) o[j] = acc[j];
}

extern "C" void kernel_launch(void* const* d_in, const int* in_sizes, int n_in,
                              void* d_out, int out_size, void* d_ws, size_t ws_size,
                              hipStream_t stream) {
    const float* q    = (const float*)d_in[0];
    const float* relh = (const float*)d_in[3];
    const float* relw = (const float*)d_in[4];
    float* out = (float*)d_out;

    // grid: 16 c-groups x 128 (b,h); same-bh blocks are 128 apart -> same XCD
    relpos_kernel<<<dim3(2048), dim3(256), 0, stream>>>(q, relh, relw, out);
}

// Round 5
// 57.146 us; speedup vs baseline: 1.6782x; 1.0451x over previous
//
#include <hip/hip_runtime.h>
#include <stdint.h>

#define NS 9

// out[b,h,A,C,j] = sum_d q[b,h,A,C,d]*relw[63+j-C,d] + q[b,h,C,A,d]*relh[63+j-C,d]
// Block = 4 waves, wave wvu owns C = 4*g + wvu; lane = A.
// v5 = v3's per-wave 4-stage q pipeline + rel tables in LDS (v4 concept), but
// rel staging uses ONLY size-16 global_load_lds (size-12's lane stride is not
// HW-verified and produced v4's corruption): stage a 16-row window
// [base, base+16) of each 72-row table, base = max(0, 56-c0)  (c0<=60 so the
// window is always in-bounds and covers rows 63-c .. 71-c for all 4 waves).
// Each wave copies 1 KiB chunk wvu of each 4-KiB table slice -> 2 instrs/wave,
// uniform vmcnt across waves; published by vmcnt(16) + raw s_barrier.
// Compute reads rel via ds_read_b128 at wave-uniform addresses (broadcast,
// in-order, conflict-free) instead of 288 s_load_dwordx4/wave (v1-v3 maxed
// SGPR_Count=112 and stalled on scalar-cache thrash + lgkmcnt(0) drains).

__device__ __forceinline__ void gload_lds16(const void* g, void* l) {
    __builtin_amdgcn_global_load_lds(
        (const __attribute__((address_space(1))) uint32_t*)g,
        (__attribute__((address_space(3))) uint32_t*)l, 16, 0, 0);
}

#define WAIT_VMCNT(N) do { \
    __builtin_amdgcn_sched_barrier(0); \
    asm volatile("s_waitcnt vmcnt(" #N ")" ::: "memory"); \
    __builtin_amdgcn_sched_barrier(0); } while (0)

#define WAIT_LGKM0 do { \
    __builtin_amdgcn_sched_barrier(0); \
    asm volatile("s_waitcnt lgkmcnt(0)" ::: "memory"); \
    __builtin_amdgcn_sched_barrier(0); } while (0)

__global__ __launch_bounds__(256, 2) void relpos_kernel(
    const float* __restrict__ q,
    const float* __restrict__ relh,
    const float* __restrict__ relw,
    float* __restrict__ out)
{
    __shared__ float qt[4][2][2048];     // 64 KiB: 4 waves x 2 bufs x 8 KiB
    __shared__ float rel_l[2][16][64];   // 8 KiB: {relh,relw} rows base..base+15

    const int bh   = blockIdx.x & 127;   // b*8 + h
    const int g    = blockIdx.x >> 7;    // c-group 0..15
    const int lane = threadIdx.x & 63;   // = A
    const int wvu  = __builtin_amdgcn_readfirstlane(threadIdx.x >> 6);
    const int c0   = g << 2;
    const int c    = __builtin_amdgcn_readfirstlane(c0 + wvu);
    const int a    = lane;
    const int base = (c0 < 56) ? (56 - c0) : 0;       // uniform, <= 56
    const int rowoff = 63 - c - base;                 // wave-uniform, 0..7

    const size_t qslab = (size_t)bh << 18;            // bh * 64*64*64

    // ---- rel staging: wave wvu copies 1 KiB chunk wvu of each 4 KiB slice ----
    {
        const char* hs = (const char*)(relh + (size_t)base * 64) + (wvu << 10) + (lane << 4);
        const char* ws = (const char*)(relw + (size_t)base * 64) + (wvu << 10) + (lane << 4);
        gload_lds16(hs, (char*)&rel_l[0][0][0] + (wvu << 10));
        gload_lds16(ws, (char*)&rel_l[1][0][0] + (wvu << 10));
    }
    __builtin_amdgcn_sched_barrier(0);   // keep rel loads oldest in vmcnt order

    float* const buf0 = &qt[wvu][0][0];
    float* const buf1 = &qt[wvu][1][0];

    float acc[NS];
#pragma unroll
    for (int j = 0; j < NS; ++j) acc[j] = 0.f;

    // ---- q stage: 8 x global_load_lds (1 KiB each) per 8 KiB sub-tile ----
    // phase 0: q2 row r = q[bh, c, r, :]   phase 1: q1 row r = q[bh, r, c, :]
    auto stage = [&](float* buf, int phase, int h) {
#pragma unroll
        for (int i = 0; i < 8; ++i) {
            const int ck  = (i << 6) | lane;        // chunk-slot 0..511
            const int r   = ck >> 3;                // A-row 0..63
            const int gch = (ck & 7) ^ (r & 7);     // pre-swizzled source chunk
            const float* gp = (phase == 0)
                ? q + qslab + (size_t)c * 4096 + (size_t)r * 64 + (h << 5) + (gch << 2)
                : q + qslab + (size_t)r * 4096 + (size_t)c * 64 + (h << 5) + (gch << 2);
            gload_lds16(gp, buf + (i << 8));        // linear dest, i*1024 B
        }
    };

    auto compute = [&](const float* buf, int t, int h) {
        const float* relbase = &rel_l[t][rowoff][0];   // wave-uniform LDS addr
#pragma unroll
        for (int ch = 0; ch < 8; ++ch) {
            const float4 x = *reinterpret_cast<const float4*>(
                &buf[(a << 5) + ((ch ^ (a & 7)) << 2)]);
#pragma unroll
            for (int j = 0; j < NS; ++j) {
                const float4 rv = *reinterpret_cast<const float4*>(
                    &relbase[(j << 6) + (h << 5) + (ch << 2)]);
                acc[j] = fmaf(x.x, rv.x, fmaf(x.y, rv.y,
                         fmaf(x.z, rv.z, fmaf(x.w, rv.w, acc[j]))));
            }
        }
    };

    // ---- pipeline: rel(2 oldest) then 4 q-stages, 2-deep ----
    stage(buf0, 0, 0);            // S0  (outstanding: 2 rel + 8)
    stage(buf1, 0, 1);            // S1  (outstanding: 2 rel + 16)
    WAIT_VMCNT(16);               // rel landed (2 oldest of 18)
    __builtin_amdgcn_s_barrier(); // publish rel to all waves (raw, no drain)
    WAIT_VMCNT(8);                // S0 landed
    compute(buf0, 0, 0);          // term2 (relh), d-half 0
    WAIT_LGKM0;                   // buf0 reads done before overwrite
    stage(buf0, 1, 0);            // S2
    WAIT_VMCNT(8);                // S1 landed
    compute(buf1, 0, 1);          // term2 (relh), d-half 1
    WAIT_LGKM0;
    stage(buf1, 1, 1);            // S3
    WAIT_VMCNT(8);                // S2 landed
    compute(buf0, 1, 0);          // term1 (relw), d-half 0
    WAIT_VMCNT(0);                // S3 landed
    compute(buf1, 1, 1);          // term1 (relw), d-half 1

    // ---- store ----
    float* __restrict__ o = out + (((size_t)bh * 64 + a) * 64 + c) * NS;
#pragma unroll
    for (int j = 0; j < NS; ++j) o[j] = acc[j];
}

extern "C" void kernel_launch(void* const* d_in, const int* in_sizes, int n_in,
                              void* d_out, int out_size, void* d_ws, size_t ws_size,
                              hipStream_t stream) {
    const float* q    = (const float*)d_in[0];
    const float* relh = (const float*)d_in[3];
    const float* relw = (const float*)d_in[4];
    float* out = (float*)d_out;

    // grid: 16 c-groups x 128 (b,h); same-bh blocks are 128 apart -> same XCD
    relpos_kernel<<<dim3(2048), dim3(256), 0, stream>>>(q, relh, relw, out);
}

// Round 7
// 51.243 us; speedup vs baseline: 1.8715x; 1.1152x over previous
//
#include <hip/hip_runtime.h>
#include <stdint.h>

#define NS 9

typedef _Float16 f16x8 __attribute__((ext_vector_type(8)));
typedef float    f32x4 __attribute__((ext_vector_type(4)));

#define SBAR __builtin_amdgcn_sched_barrier(0)
#define WAIT_VM(N) do { SBAR; asm volatile("s_waitcnt vmcnt(" #N ")" ::: "memory"); SBAR; } while (0)
#define WAIT_LGKM0 do { SBAR; asm volatile("s_waitcnt lgkmcnt(0)" ::: "memory"); SBAR; } while (0)

// f32 pair -> packed f16x2 bits (cvt_pkrtz returns __fp16x2; bit-cast to u32)
__device__ __forceinline__ unsigned int pk(float a, float b) {
    return __builtin_bit_cast(unsigned int, __builtin_amdgcn_cvt_pkrtz(a, b));
}

// out[b,h,A,C,j] = sum_d q[b,h,A,C,d]*relw[63+j-C,d] + q[b,h,C,A,d]*relh[63+j-C,d]
// v7 = v6 with the cvt_pkrtz typing fixed (compile error only; logic identical).
// Per-wave GEMM on the MFMA pipe (v2-v5 were LDS-issue-bound: 320
// ds_read_b128/thread of broadcast rel ~= 34-51us/CU on the shared LDS pipe).
// Per wave (one C): out[64 A][9 j] = X(64x64) * R^T(64x9pad16), f16 inputs,
// f32 accum, via 16x mfma_f32_16x16x32_f16 (4 m-blocks x 2 K-steps x 2 terms).
// q tiles reg-staged f32->cvt_pkrtz->f16 LDS (XOR chunk swizzle s=koff^(row&7));
// rel staged once per block to LDS f16, B-frags held in VGPRs for the whole
// kernel. Counted-vmcnt per-wave pipeline, one s_barrier (rel publish) only.
// Layouts (gfx950 16x16x32): A row=lane&15,k=8*(lane>>4)+i ; B col=lane&15,
// same k ; C/D col(j)=lane&15, row(a)=(lane>>4)*4+reg  [m89-verified].

__global__ __launch_bounds__(256, 3) void relpos_kernel(
    const float* __restrict__ q,
    const float* __restrict__ relh,
    const float* __restrict__ relw,
    float* __restrict__ out)
{
    __shared__ uint4 qt[4][2][256];    // 4 waves x 2 bufs x 4 KiB f16 (32 rows)
    __shared__ uint4 rel_l[2][16][8];  // 2 tables x 16 rows x 128 B f16

    const int bh   = blockIdx.x & 127;  // b*8 + h
    const int g    = blockIdx.x >> 7;   // c-group 0..15
    const int tid  = threadIdx.x;
    const int lane = tid & 63;
    const int wvu  = __builtin_amdgcn_readfirstlane(tid >> 6);
    const int c0   = g << 2;
    const int c    = __builtin_amdgcn_readfirstlane(c0 + wvu);
    const int base = (c0 < 56) ? (56 - c0) : 0;   // rel window start, uniform
    const int rowoff = 63 - c - base;             // wave-uniform, 0..7

    const float* __restrict__ qs = q + ((size_t)bh << 18);

    // ---- issue rel loads first (2 per thread, oldest in vmcnt order) ----
    const int rt   = tid >> 7;          // 0: relh (waves 0,1)  1: relw (2,3)
    const int rrow = (tid >> 3) & 15;
    const int rs   = tid & 7;
    const int rg   = rs ^ (rrow & 7);
    const float* rsrc = (rt ? relw : relh) + (size_t)(base + rrow) * 64 + rg * 8;
    const float4 relv0 = *reinterpret_cast<const float4*>(rsrc);
    const float4 relv1 = *reinterpret_cast<const float4*>(rsrc + 4);
    SBAR;

    uint4* const buf0 = &qt[wvu][0][0];
    uint4* const buf1 = &qt[wvu][1][0];

    // q half-tile issue: 8 x global_load_dwordx4 into regs.
    // term0 (q2): X[a]=q[bh,c,a,:]   term1 (q1): X[a]=q[bh,a,c,:]
    auto issueT0 = [&](int R, float4* dst) {
#pragma unroll
        for (int ii = 0; ii < 4; ++ii) {
            const int c16 = lane + (ii << 6);
            const int r   = c16 >> 3;                 // row_local 0..31
            const int g16 = (c16 & 7) ^ (r & 7);
            const float* s0 = qs + (size_t)c * 4096 + (size_t)(32 * R + r) * 64 + g16 * 8;
            dst[2 * ii]     = *reinterpret_cast<const float4*>(s0);
            dst[2 * ii + 1] = *reinterpret_cast<const float4*>(s0 + 4);
        }
    };
    auto issueT1 = [&](int R, float4* dst) {
#pragma unroll
        for (int ii = 0; ii < 4; ++ii) {
            const int c16 = lane + (ii << 6);
            const int r   = c16 >> 3;
            const int g16 = (c16 & 7) ^ (r & 7);
            const float* s0 = qs + (size_t)(32 * R + r) * 4096 + (size_t)c * 64 + g16 * 8;
            dst[2 * ii]     = *reinterpret_cast<const float4*>(s0);
            dst[2 * ii + 1] = *reinterpret_cast<const float4*>(s0 + 4);
        }
    };
    auto cvtWrite = [&](const float4* src, uint4* buf) {
#pragma unroll
        for (int ii = 0; ii < 4; ++ii) {
            const int c16 = lane + (ii << 6);
            uint4 w;
            w.x = pk(src[2 * ii].x,     src[2 * ii].y);
            w.y = pk(src[2 * ii].z,     src[2 * ii].w);
            w.z = pk(src[2 * ii + 1].x, src[2 * ii + 1].y);
            w.w = pk(src[2 * ii + 1].z, src[2 * ii + 1].w);
            buf[c16] = w;                              // ds_write_b128, linear
        }
    };
    auto readA = [&](const uint4* buf, int mp, int ks) -> f16x8 {
        const int rl = mp * 16 + (lane & 15);
        const int k4 = ks * 4 + (lane >> 4);
        return __builtin_bit_cast(f16x8, buf[rl * 8 + (k4 ^ (rl & 7))]);
    };
    auto readB = [&](int T, int ks) -> f16x8 {
        int rl = rowoff + (lane & 15); if (rl > 15) rl = 15;  // pad cols clamp
        const int k4 = ks * 4 + (lane >> 4);
        return __builtin_bit_cast(f16x8, rel_l[T][rl][k4 ^ (rl & 7)]);
    };

    float4 hA[8], hB[8];
    f32x4 acc0 = {0.f, 0.f, 0.f, 0.f}, acc1 = acc0, acc2 = acc0, acc3 = acc0;

    issueT0(0, hA); SBAR;            // H0   [vm: 2 rel + 8]
    issueT0(1, hB); SBAR;            // H1   [18]

    WAIT_VM(16);                     // rel f32 in regs
    {
        uint4 w;
        w.x = pk(relv0.x, relv0.y);
        w.y = pk(relv0.z, relv0.w);
        w.z = pk(relv1.x, relv1.y);
        w.w = pk(relv1.z, relv1.w);
        rel_l[rt][rrow][rs] = w;
    }
    WAIT_LGKM0;
    __builtin_amdgcn_s_barrier();    // publish rel (only block-wide sync)

    const f16x8 b00 = readB(0, 0), b01 = readB(0, 1);
    const f16x8 b10 = readB(1, 0), b11 = readB(1, 1);

    WAIT_VM(8);                      // H0 regs ready
    cvtWrite(hA, buf0);
    issueT1(0, hA); SBAR;            // H2   [vm: 8(H1)+8 = 16]
    WAIT_LGKM0;                      // b-frags in regs, buf0 written
    {
        f16x8 a0 = readA(buf0, 0, 0), a1 = readA(buf0, 0, 1);
        f16x8 a2 = readA(buf0, 1, 0), a3 = readA(buf0, 1, 1);
        WAIT_LGKM0;
        acc0 = __builtin_amdgcn_mfma_f32_16x16x32_f16(a0, b00, acc0, 0, 0, 0);
        acc0 = __builtin_amdgcn_mfma_f32_16x16x32_f16(a1, b01, acc0, 0, 0, 0);
        acc1 = __builtin_amdgcn_mfma_f32_16x16x32_f16(a2, b00, acc1, 0, 0, 0);
        acc1 = __builtin_amdgcn_mfma_f32_16x16x32_f16(a3, b01, acc1, 0, 0, 0);
    }
    WAIT_VM(8);                      // H1 regs ready (H2 still out)
    cvtWrite(hB, buf1);
    issueT1(1, hB); SBAR;            // H3   [16]
    WAIT_LGKM0;
    {
        f16x8 a0 = readA(buf1, 0, 0), a1 = readA(buf1, 0, 1);
        f16x8 a2 = readA(buf1, 1, 0), a3 = readA(buf1, 1, 1);
        WAIT_LGKM0;
        acc2 = __builtin_amdgcn_mfma_f32_16x16x32_f16(a0, b00, acc2, 0, 0, 0);
        acc2 = __builtin_amdgcn_mfma_f32_16x16x32_f16(a1, b01, acc2, 0, 0, 0);
        acc3 = __builtin_amdgcn_mfma_f32_16x16x32_f16(a2, b00, acc3, 0, 0, 0);
        acc3 = __builtin_amdgcn_mfma_f32_16x16x32_f16(a3, b01, acc3, 0, 0, 0);
    }
    WAIT_VM(8);                      // H2 regs ready
    cvtWrite(hA, buf0);              // WAR ok: H0 frag reads completed above
    WAIT_LGKM0;
    {
        f16x8 a0 = readA(buf0, 0, 0), a1 = readA(buf0, 0, 1);
        f16x8 a2 = readA(buf0, 1, 0), a3 = readA(buf0, 1, 1);
        WAIT_LGKM0;
        acc0 = __builtin_amdgcn_mfma_f32_16x16x32_f16(a0, b10, acc0, 0, 0, 0);
        acc0 = __builtin_amdgcn_mfma_f32_16x16x32_f16(a1, b11, acc0, 0, 0, 0);
        acc1 = __builtin_amdgcn_mfma_f32_16x16x32_f16(a2, b10, acc1, 0, 0, 0);
        acc1 = __builtin_amdgcn_mfma_f32_16x16x32_f16(a3, b11, acc1, 0, 0, 0);
    }
    WAIT_VM(0);                      // H3 regs ready
    cvtWrite(hB, buf1);
    WAIT_LGKM0;
    {
        f16x8 a0 = readA(buf1, 0, 0), a1 = readA(buf1, 0, 1);
        f16x8 a2 = readA(buf1, 1, 0), a3 = readA(buf1, 1, 1);
        WAIT_LGKM0;
        acc2 = __builtin_amdgcn_mfma_f32_16x16x32_f16(a0, b10, acc2, 0, 0, 0);
        acc2 = __builtin_amdgcn_mfma_f32_16x16x32_f16(a1, b11, acc2, 0, 0, 0);
        acc3 = __builtin_amdgcn_mfma_f32_16x16x32_f16(a2, b10, acc3, 0, 0, 0);
        acc3 = __builtin_amdgcn_mfma_f32_16x16x32_f16(a3, b11, acc3, 0, 0, 0);
    }

    // ---- store: lane holds cols j=lane&15 (<9), rows a=(lane>>4)*4+reg ----
    const int j = lane & 15;
    if (j < NS) {
        const int ar = (lane >> 4) << 2;
        const size_t ob = (size_t)bh << 6;
#pragma unroll
        for (int r = 0; r < 4; ++r) {
            out[((ob + ( 0 + ar + r)) * 64 + c) * NS + j] = acc0[r];
            out[((ob + (16 + ar + r)) * 64 + c) * NS + j] = acc1[r];
            out[((ob + (32 + ar + r)) * 64 + c) * NS + j] = acc2[r];
            out[((ob + (48 + ar + r)) * 64 + c) * NS + j] = acc3[r];
        }
    }
}

extern "C" void kernel_launch(void* const* d_in, const int* in_sizes, int n_in,
                              void* d_out, int out_size, void* d_ws, size_t ws_size,
                              hipStream_t stream) {
    const float* q    = (const float*)d_in[0];
    const float* relh = (const float*)d_in[3];
    const float* relw = (const float*)d_in[4];
    float* out = (float*)d_out;

    // grid: 16 c-groups x 128 (b,h); same-bh blocks are 128 apart -> same XCD
    relpos_kernel<<<dim3(2048), dim3(256), 0, stream>>>(q, relh, relw, out);
}